// Round 1
// baseline (13830.600 us; speedup 1.0000x reference)
//
#include <hip/hip_runtime.h>
#include <math.h>

#define B_ 32
#define S_ 256
#define E_ 256
#define H_ 512
#define L_ 1024
#define G4 2048      // 4*H
// workspace layout (in floats)
#define N_HE    (B_*L_*H_)             // 16777216
#define OFF_HE  0
#define OFF_H   (OFF_HE + N_HE)
#define OFF_C   (OFF_H + B_*H_)
#define OFF_ATT (OFF_C + B_*H_)
#define OFF_PG  (OFF_ATT + B_*H_)
#define N_PG    (8*B_*G4)              // 524288
#define OFF_PSE (OFF_PG + N_PG)
#define N_PSE   (4*B_*H_)              // 65536
#define OFF_E   (OFF_PSE + N_PSE)
#define N_E     (B_*L_)

// ---------------- zero init for h, c, att ----------------
__global__ void k_zero(float* __restrict__ p, int n) {
    int i = blockIdx.x * blockDim.x + threadIdx.x;
    if (i < n) p[i] = 0.f;
}

// ---------------- h_e = encoder_h @ W_h.T + b_h ----------------
// C[m,n] = sum_k A[m,k]*W[n,k] + b[n];  M=B*L=32768, N=512, K=512
__global__ __launch_bounds__(256) void k_he(const float* __restrict__ A,
                                            const float* __restrict__ W,
                                            const float* __restrict__ bias,
                                            float* __restrict__ C) {
    __shared__ float As[64][36];   // row stride 144B (16B aligned)
    __shared__ float Bs[64][37];   // padded 37 to break 8-way bank conflict
    const int m0 = blockIdx.y * 64;
    const int n0 = blockIdx.x * 64;
    const int tid = threadIdx.x;
    const int tx = tid & 15, ty = tid >> 4;
    float acc[4][4] = {};
    for (int kk = 0; kk < 512; kk += 32) {
        #pragma unroll
        for (int i = 0; i < 2; ++i) {
            int idx = tid + i * 256;
            int r = idx >> 3, c4 = (idx & 7) << 2;
            float4 va = *(const float4*)(A + (size_t)(m0 + r) * 512 + kk + c4);
            *(float4*)&As[r][c4] = va;
            float4 vb = *(const float4*)(W + (size_t)(n0 + r) * 512 + kk + c4);
            Bs[r][c4 + 0] = vb.x; Bs[r][c4 + 1] = vb.y;
            Bs[r][c4 + 2] = vb.z; Bs[r][c4 + 3] = vb.w;
        }
        __syncthreads();
        #pragma unroll
        for (int k2 = 0; k2 < 32; ++k2) {
            float a[4], b[4];
            #pragma unroll
            for (int i = 0; i < 4; ++i) a[i] = As[ty * 4 + i][k2];
            #pragma unroll
            for (int j = 0; j < 4; ++j) b[j] = Bs[tx * 4 + j][k2];
            #pragma unroll
            for (int i = 0; i < 4; ++i)
                #pragma unroll
                for (int j = 0; j < 4; ++j) acc[i][j] += a[i] * b[j];
        }
        __syncthreads();
    }
    float bj[4];
    #pragma unroll
    for (int j = 0; j < 4; ++j) bj[j] = bias[n0 + tx * 4 + j];
    #pragma unroll
    for (int i = 0; i < 4; ++i) {
        float4 r4;
        r4.x = acc[i][0] + bj[0]; r4.y = acc[i][1] + bj[1];
        r4.z = acc[i][2] + bj[2]; r4.w = acc[i][3] + bj[3];
        *(float4*)(C + (size_t)(m0 + ty * 4 + i) * 512 + n0 + tx * 4) = r4;
    }
}

// ---------------- gates partial: pg[kz][b][row] = sum_{K range} W[row,:]*x[b,:] ----------------
// x = [y_t (256) | att (512) | h (512)], W = [W_ih | W_hh].  grid (32 row-tiles, 8 K-splits)
__global__ __launch_bounds__(256) void k_gates(const float* __restrict__ y,
                                               const float* __restrict__ att,
                                               const float* __restrict__ h,
                                               const float* __restrict__ Wih,
                                               const float* __restrict__ Whh,
                                               float* __restrict__ pg, int t) {
    __shared__ float xs[32][36];
    __shared__ float Ws[64][36];
    const int tid = threadIdx.x;
    const int r = tid & 63;         // local gate row
    const int b0 = (tid >> 6) * 8;  // batch group base
    const int r0 = blockIdx.x * 64;
    const int kbeg = blockIdx.y * 160;
    float acc[8] = {};
    for (int kk = kbeg; kk < kbeg + 160; kk += 32) {
        {   // stage x chunk: 32 b x 32 j
            int b = tid >> 3, j0 = (tid & 7) << 2;
            float4 v;
            if (kk < 256)      v = *(const float4*)(y + (size_t)b * (S_ * E_) + t * E_ + kk + j0);
            else if (kk < 768) v = *(const float4*)(att + b * H_ + (kk - 256) + j0);
            else               v = *(const float4*)(h + b * H_ + (kk - 768) + j0);
            *(float4*)&xs[b][j0] = v;
        }
        #pragma unroll
        for (int i = 0; i < 2; ++i) {  // stage W chunk: 64 rows x 32
            int idx = tid + i * 256;
            int rr = idx >> 3, c4 = (idx & 7) << 2;
            int grow = r0 + rr;
            float4 v;
            if (kk < 768) v = *(const float4*)(Wih + (size_t)grow * 768 + kk + c4);
            else          v = *(const float4*)(Whh + (size_t)grow * 512 + (kk - 768) + c4);
            *(float4*)&Ws[rr][c4] = v;
        }
        __syncthreads();
        #pragma unroll
        for (int j = 0; j < 32; j += 4) {
            float4 w4 = *(float4*)&Ws[r][j];
            #pragma unroll
            for (int bb = 0; bb < 8; ++bb) {
                float4 x4 = *(float4*)&xs[b0 + bb][j];
                acc[bb] += w4.x * x4.x + w4.y * x4.y + w4.z * x4.z + w4.w * x4.w;
            }
        }
        __syncthreads();
    }
    #pragma unroll
    for (int bb = 0; bb < 8; ++bb)
        pg[(size_t)blockIdx.y * (B_ * G4) + (b0 + bb) * G4 + r0 + r] = acc[bb];
}

// ---------------- LSTM pointwise: sum partials, update c,h, write h_seq ----------------
__global__ void k_lstm(const float* __restrict__ pg,
                       const float* __restrict__ bih, const float* __restrict__ bhh,
                       float* __restrict__ c, float* __restrict__ h,
                       float* __restrict__ out_h, int t) {
    int idx = blockIdx.x * blockDim.x + threadIdx.x;  // 0..16383
    int b = idx >> 9, d = idx & 511;
    float gi = bih[d] + bhh[d];
    float gf = bih[512 + d] + bhh[512 + d];
    float gg = bih[1024 + d] + bhh[1024 + d];
    float go = bih[1536 + d] + bhh[1536 + d];
    #pragma unroll
    for (int s = 0; s < 8; ++s) {
        const float* p = pg + (size_t)s * (B_ * G4) + b * G4;
        gi += p[d]; gf += p[512 + d]; gg += p[1024 + d]; go += p[1536 + d];
    }
    float si = 1.f / (1.f + expf(-gi));
    float sf = 1.f / (1.f + expf(-gf));
    float so = 1.f / (1.f + expf(-go));
    float cc = sf * c[idx] + si * tanhf(gg);
    float hh = so * tanhf(cc);
    c[idx] = cc;
    h[idx] = hh;
    out_h[(size_t)b * (S_ * H_) + t * H_ + d] = hh;
}

// ---------------- s_e partials: pse[kz][b][row] ----------------  grid (8 row-tiles, 4 K-splits)
__global__ __launch_bounds__(256) void k_se(const float* __restrict__ h,
                                            const float* __restrict__ Ws_,
                                            float* __restrict__ pse) {
    __shared__ float xs[32][36];
    __shared__ float Ws[64][36];
    const int tid = threadIdx.x;
    const int r = tid & 63;
    const int b0 = (tid >> 6) * 8;
    const int r0 = blockIdx.x * 64;
    const int kbeg = blockIdx.y * 128;
    float acc[8] = {};
    for (int kk = kbeg; kk < kbeg + 128; kk += 32) {
        {
            int b = tid >> 3, j0 = (tid & 7) << 2;
            *(float4*)&xs[b][j0] = *(const float4*)(h + b * H_ + kk + j0);
        }
        #pragma unroll
        for (int i = 0; i < 2; ++i) {
            int idx = tid + i * 256;
            int rr = idx >> 3, c4 = (idx & 7) << 2;
            *(float4*)&Ws[rr][c4] = *(const float4*)(Ws_ + (size_t)(r0 + rr) * 512 + kk + c4);
        }
        __syncthreads();
        #pragma unroll
        for (int j = 0; j < 32; j += 4) {
            float4 w4 = *(float4*)&Ws[r][j];
            #pragma unroll
            for (int bb = 0; bb < 8; ++bb) {
                float4 x4 = *(float4*)&xs[b0 + bb][j];
                acc[bb] += w4.x * x4.x + w4.y * x4.y + w4.z * x4.z + w4.w * x4.w;
            }
        }
        __syncthreads();
    }
    #pragma unroll
    for (int bb = 0; bb < 8; ++bb)
        pse[(size_t)blockIdx.y * (B_ * H_) + (b0 + bb) * H_ + r0 + r] = acc[bb];
}

// ---------------- e[b,l] = dot(s_e[b], h_e[b,l,:]) ----------------  grid (8 l-chunks, 32 b)
__global__ __launch_bounds__(256) void k_e(const float* __restrict__ pse,
                                           const float* __restrict__ bs,
                                           const float* __restrict__ he,
                                           float* __restrict__ e) {
    __shared__ float ses[512];
    __shared__ float tile[128][68];
    const int tid = threadIdx.x;
    const int b = blockIdx.y;
    const int l0 = blockIdx.x * 128;
    for (int i = tid; i < 512; i += 256) {
        float v = bs[i];
        #pragma unroll
        for (int s = 0; s < 4; ++s) v += pse[(size_t)s * (B_ * H_) + b * H_ + i];
        ses[i] = v;
    }
    __syncthreads();
    float acc = 0.f;
    for (int kc = 0; kc < 512; kc += 64) {
        #pragma unroll
        for (int i = 0; i < 8; ++i) {
            int fi = tid + i * 256;
            int rr = fi >> 4, c4 = (fi & 15) << 2;
            *(float4*)&tile[rr][c4] =
                *(const float4*)(he + ((size_t)b * L_ + l0 + rr) * H_ + kc + c4);
        }
        __syncthreads();
        if (tid < 128) {
            #pragma unroll
            for (int k = 0; k < 64; k += 4) {
                float4 hv = *(float4*)&tile[tid][k];
                float4 sv = *(float4*)&ses[kc + k];
                acc += hv.x * sv.x + hv.y * sv.y + hv.z * sv.z + hv.w * sv.w;
            }
        }
        __syncthreads();
    }
    if (tid < 128) e[b * L_ + l0 + tid] = acc;
}

// ---------------- softmax + att[b,:] = sum_l a_l * h_e[b,l,:] ----------------  grid (8 h-chunks, 32 b)
__global__ __launch_bounds__(256) void k_att(const float* __restrict__ e,
                                             const float* __restrict__ he,
                                             float* __restrict__ att,
                                             float* __restrict__ out_att, int t) {
    __shared__ float als[1024];
    __shared__ float red[256];
    __shared__ float part[4][64];
    const int tid = threadIdx.x;
    const int b = blockIdx.y;
    const int h0 = blockIdx.x * 64;
    float m = -1e30f;
    for (int i = tid; i < 1024; i += 256) {
        float v = e[b * L_ + i];
        als[i] = v;
        m = fmaxf(m, v);
    }
    red[tid] = m; __syncthreads();
    for (int s = 128; s > 0; s >>= 1) {
        if (tid < s) red[tid] = fmaxf(red[tid], red[tid + s]);
        __syncthreads();
    }
    m = red[0]; __syncthreads();
    float zs = 0.f;
    for (int i = tid; i < 1024; i += 256) {
        float p = expf(als[i] - m);
        als[i] = p;
        zs += p;
    }
    red[tid] = zs; __syncthreads();
    for (int s = 128; s > 0; s >>= 1) {
        if (tid < s) red[tid] += red[tid + s];
        __syncthreads();
    }
    const float invZ = 1.f / red[0];
    __syncthreads();
    // weighted sum over l; thread t: h' = t&63, l-range (t>>6)*256..+256
    const int hh = tid & 63, lg = tid >> 6;
    float acc = 0.f;
    for (int l = lg * 256; l < lg * 256 + 256; ++l)
        acc += als[l] * he[((size_t)b * L_ + l) * H_ + h0 + hh];
    part[lg][hh] = acc; __syncthreads();
    if (tid < 64) {
        float v = (part[0][tid] + part[1][tid] + part[2][tid] + part[3][tid]) * invZ;
        att[b * H_ + h0 + tid] = v;
        out_att[(size_t)b * (S_ * H_) + t * H_ + h0 + tid] = v;
    }
}

extern "C" void kernel_launch(void* const* d_in, const int* in_sizes, int n_in,
                              void* d_out, int out_size, void* d_ws, size_t ws_size,
                              hipStream_t stream) {
    const float* y   = (const float*)d_in[0];
    const float* enc = (const float*)d_in[1];
    const float* Wih = (const float*)d_in[2];
    const float* bih = (const float*)d_in[3];
    const float* Whh = (const float*)d_in[4];
    const float* bhh = (const float*)d_in[5];
    const float* Ws_ = (const float*)d_in[6];
    const float* bs  = (const float*)d_in[7];
    const float* Wh  = (const float*)d_in[8];
    const float* bh  = (const float*)d_in[9];

    float* ws   = (float*)d_ws;
    float* he   = ws + OFF_HE;
    float* h    = ws + OFF_H;
    float* c    = ws + OFF_C;
    float* att  = ws + OFF_ATT;
    float* pg   = ws + OFF_PG;
    float* pse  = ws + OFF_PSE;
    float* e    = ws + OFF_E;
    float* out_h   = (float*)d_out;
    float* out_att = out_h + (size_t)B_ * S_ * H_;

    k_zero<<<(3 * B_ * H_ + 255) / 256, 256, 0, stream>>>(h, 3 * B_ * H_);
    k_he<<<dim3(H_ / 64, (B_ * L_) / 64), 256, 0, stream>>>(enc, Wh, bh, he);
    for (int t = 0; t < S_; ++t) {
        k_gates<<<dim3(32, 8), 256, 0, stream>>>(y, att, h, Wih, Whh, pg, t);
        k_lstm<<<(B_ * H_) / 256, 256, 0, stream>>>(pg, bih, bhh, c, h, out_h, t);
        k_se<<<dim3(8, 4), 256, 0, stream>>>(h, Ws_, pse);
        k_e<<<dim3(8, 32), 256, 0, stream>>>(pse, bs, he, e);
        k_att<<<dim3(8, 32), 256, 0, stream>>>(e, he, att, out_att, t);
    }
}

// Round 2
// 10800.620 us; speedup vs baseline: 1.2805x; 1.2805x over previous
//
#include <hip/hip_runtime.h>
#include <math.h>

typedef unsigned short u16;
typedef unsigned int   u32;

#define B_ 32
#define S_ 256
#define E_ 256
#define H_ 512
#define L_ 1024
#define G4 2048      // 4*H

// ---- workspace layout (in floats) ----
#define OFF_HEB  0                         // he bf16: 16,777,216 u16 = 8,388,608 floats
#define OFF_WIHB 8388608                   // Wih bf16: 1,572,864 u16 = 786,432 floats
#define OFF_WHHB 9175040                   // Whh bf16: 1,048,576 u16 = 524,288 floats
#define OFF_H    9699328
#define OFF_C    9715712
#define OFF_ATT  9732096
#define OFF_PG   9748480                   // 8*32*2048 = 524,288
#define OFF_PSE  10272768                  // 4*32*512  = 65,536
#define OFF_PA   10338304                  // 32*16*520 = 266,240

__device__ inline u16 f2bf(float x) {
    u32 u = __float_as_uint(x);
    u += 0x7fffu + ((u >> 16) & 1u);
    return (u16)(u >> 16);
}
__device__ inline float bflo(u32 q) { return __uint_as_float(q << 16); }
__device__ inline float bfhi(u32 q) { return __uint_as_float(q & 0xffff0000u); }

// ---------------- zero init for h, c, att ----------------
__global__ void k_zero(float* __restrict__ p, int n) {
    int i = blockIdx.x * blockDim.x + threadIdx.x;
    if (i < n) p[i] = 0.f;
}

// ---------------- one-time: convert W_ih, W_hh to bf16 ----------------
__global__ void k_cvtw(const float* __restrict__ Wih, const float* __restrict__ Whh,
                       u16* __restrict__ wihb, u16* __restrict__ whhb) {
    int i = (blockIdx.x * 256 + threadIdx.x) * 4;
    if (i < 1572864) {
        float4 v = *(const float4*)(Wih + i);
        ushort4 r; r.x = f2bf(v.x); r.y = f2bf(v.y); r.z = f2bf(v.z); r.w = f2bf(v.w);
        *(ushort4*)(wihb + i) = r;
    } else {
        int j = i - 1572864;
        float4 v = *(const float4*)(Whh + j);
        ushort4 r; r.x = f2bf(v.x); r.y = f2bf(v.y); r.z = f2bf(v.z); r.w = f2bf(v.w);
        *(ushort4*)(whhb + j) = r;
    }
}

// ---------------- h_e = encoder_h @ W_h.T + b_h  (bf16 out) ----------------
__global__ __launch_bounds__(256) void k_he(const float* __restrict__ A,
                                            const float* __restrict__ W,
                                            const float* __restrict__ bias,
                                            u16* __restrict__ C) {
    __shared__ float As[64][36];
    __shared__ float Bs[64][37];
    const int m0 = blockIdx.y * 64;
    const int n0 = blockIdx.x * 64;
    const int tid = threadIdx.x;
    const int tx = tid & 15, ty = tid >> 4;
    float acc[4][4] = {};
    for (int kk = 0; kk < 512; kk += 32) {
        #pragma unroll
        for (int i = 0; i < 2; ++i) {
            int idx = tid + i * 256;
            int r = idx >> 3, c4 = (idx & 7) << 2;
            float4 va = *(const float4*)(A + (size_t)(m0 + r) * 512 + kk + c4);
            *(float4*)&As[r][c4] = va;
            float4 vb = *(const float4*)(W + (size_t)(n0 + r) * 512 + kk + c4);
            Bs[r][c4 + 0] = vb.x; Bs[r][c4 + 1] = vb.y;
            Bs[r][c4 + 2] = vb.z; Bs[r][c4 + 3] = vb.w;
        }
        __syncthreads();
        #pragma unroll
        for (int k2 = 0; k2 < 32; ++k2) {
            float a[4], b[4];
            #pragma unroll
            for (int i = 0; i < 4; ++i) a[i] = As[ty * 4 + i][k2];
            #pragma unroll
            for (int j = 0; j < 4; ++j) b[j] = Bs[tx * 4 + j][k2];
            #pragma unroll
            for (int i = 0; i < 4; ++i)
                #pragma unroll
                for (int j = 0; j < 4; ++j) acc[i][j] += a[i] * b[j];
        }
        __syncthreads();
    }
    float bj[4];
    #pragma unroll
    for (int j = 0; j < 4; ++j) bj[j] = bias[n0 + tx * 4 + j];
    #pragma unroll
    for (int i = 0; i < 4; ++i) {
        ushort4 r4;
        r4.x = f2bf(acc[i][0] + bj[0]); r4.y = f2bf(acc[i][1] + bj[1]);
        r4.z = f2bf(acc[i][2] + bj[2]); r4.w = f2bf(acc[i][3] + bj[3]);
        *(ushort4*)(C + (size_t)(m0 + ty * 4 + i) * 512 + n0 + tx * 4) = r4;
    }
}

// ---------------- gates partial (bf16 weights) ----------------
// x = [y_t (256) | att (512) | h (512)].  grid (32 row-tiles, 8 K-splits)
__global__ __launch_bounds__(256) void k_gates(const float* __restrict__ y,
                                               const float* __restrict__ att,
                                               const float* __restrict__ h,
                                               const u16* __restrict__ wihb,
                                               const u16* __restrict__ whhb,
                                               float* __restrict__ pg, int t) {
    __shared__ float xs[32][36];
    __shared__ float Ws[64][36];
    const int tid = threadIdx.x;
    const int r = tid & 63;
    const int b0 = (tid >> 6) * 8;
    const int r0 = blockIdx.x * 64;
    const int kbeg = blockIdx.y * 160;
    float acc[8] = {};
    for (int kk = kbeg; kk < kbeg + 160; kk += 32) {
        {   // stage x chunk: 32 b x 32 j (fp32 global)
            int b = tid >> 3, j0 = (tid & 7) << 2;
            float4 v;
            if (kk < 256)      v = *(const float4*)(y + (size_t)b * (S_ * E_) + t * E_ + kk + j0);
            else if (kk < 768) v = *(const float4*)(att + b * H_ + (kk - 256) + j0);
            else               v = *(const float4*)(h + b * H_ + (kk - 768) + j0);
            *(float4*)&xs[b][j0] = v;
        }
        {   // stage W chunk: 64 rows x 32 from bf16, convert to f32 in LDS
            int rr = tid >> 2, c8 = (tid & 3) << 3;
            const u16* wp;
            if (kk < 768) wp = wihb + (size_t)(r0 + rr) * 768 + kk + c8;
            else          wp = whhb + (size_t)(r0 + rr) * 512 + (kk - 768) + c8;
            uint4 q = *(const uint4*)wp;
            Ws[rr][c8 + 0] = bflo(q.x); Ws[rr][c8 + 1] = bfhi(q.x);
            Ws[rr][c8 + 2] = bflo(q.y); Ws[rr][c8 + 3] = bfhi(q.y);
            Ws[rr][c8 + 4] = bflo(q.z); Ws[rr][c8 + 5] = bfhi(q.z);
            Ws[rr][c8 + 6] = bflo(q.w); Ws[rr][c8 + 7] = bfhi(q.w);
        }
        __syncthreads();
        #pragma unroll
        for (int j = 0; j < 32; j += 4) {
            float4 w4 = *(float4*)&Ws[r][j];
            #pragma unroll
            for (int bb = 0; bb < 8; ++bb) {
                float4 x4 = *(float4*)&xs[b0 + bb][j];
                acc[bb] += w4.x * x4.x + w4.y * x4.y + w4.z * x4.z + w4.w * x4.w;
            }
        }
        __syncthreads();
    }
    #pragma unroll
    for (int bb = 0; bb < 8; ++bb)
        pg[(size_t)blockIdx.y * (B_ * G4) + (b0 + bb) * G4 + r0 + r] = acc[bb];
}

// ---------------- LSTM pointwise ----------------
__global__ void k_lstm(const float* __restrict__ pg,
                       const float* __restrict__ bih, const float* __restrict__ bhh,
                       float* __restrict__ c, float* __restrict__ h,
                       float* __restrict__ out_h, int t) {
    int idx = blockIdx.x * blockDim.x + threadIdx.x;
    int b = idx >> 9, d = idx & 511;
    float gi = bih[d] + bhh[d];
    float gf = bih[512 + d] + bhh[512 + d];
    float gg = bih[1024 + d] + bhh[1024 + d];
    float go = bih[1536 + d] + bhh[1536 + d];
    #pragma unroll
    for (int s = 0; s < 8; ++s) {
        const float* p = pg + (size_t)s * (B_ * G4) + b * G4;
        gi += p[d]; gf += p[512 + d]; gg += p[1024 + d]; go += p[1536 + d];
    }
    float si = 1.f / (1.f + expf(-gi));
    float sf = 1.f / (1.f + expf(-gf));
    float so = 1.f / (1.f + expf(-go));
    float cc = sf * c[idx] + si * tanhf(gg);
    float hh = so * tanhf(cc);
    c[idx] = cc;
    h[idx] = hh;
    out_h[(size_t)b * (S_ * H_) + t * H_ + d] = hh;
}

// ---------------- s_e partials ----------------  grid (8 row-tiles, 4 K-splits)
__global__ __launch_bounds__(256) void k_se(const float* __restrict__ h,
                                            const float* __restrict__ Ws_,
                                            float* __restrict__ pse) {
    __shared__ float xs[32][36];
    __shared__ float Ws[64][36];
    const int tid = threadIdx.x;
    const int r = tid & 63;
    const int b0 = (tid >> 6) * 8;
    const int r0 = blockIdx.x * 64;
    const int kbeg = blockIdx.y * 128;
    float acc[8] = {};
    for (int kk = kbeg; kk < kbeg + 128; kk += 32) {
        {
            int b = tid >> 3, j0 = (tid & 7) << 2;
            *(float4*)&xs[b][j0] = *(const float4*)(h + b * H_ + kk + j0);
        }
        #pragma unroll
        for (int i = 0; i < 2; ++i) {
            int idx = tid + i * 256;
            int rr = idx >> 3, c4 = (idx & 7) << 2;
            *(float4*)&Ws[rr][c4] = *(const float4*)(Ws_ + (size_t)(r0 + rr) * 512 + kk + c4);
        }
        __syncthreads();
        #pragma unroll
        for (int j = 0; j < 32; j += 4) {
            float4 w4 = *(float4*)&Ws[r][j];
            #pragma unroll
            for (int bb = 0; bb < 8; ++bb) {
                float4 x4 = *(float4*)&xs[b0 + bb][j];
                acc[bb] += w4.x * x4.x + w4.y * x4.y + w4.z * x4.z + w4.w * x4.w;
            }
        }
        __syncthreads();
    }
    #pragma unroll
    for (int bb = 0; bb < 8; ++bb)
        pse[(size_t)blockIdx.y * (B_ * H_) + (b0 + bb) * H_ + r0 + r] = acc[bb];
}

// ---------------- fused attention: e + softmax-partial + ctx over 64-l chunk ----------------
// grid (16 l-chunks, 32 b), 256 threads. Single HBM/L3 read of h_e per step
// (pass 2 re-reads the 64 KB tile from hot L2).
__global__ __launch_bounds__(256) void k_attn(const float* __restrict__ pse,
                                              const float* __restrict__ bs,
                                              const u16* __restrict__ he,
                                              float* __restrict__ pa) {
    __shared__ float se[512];
    __shared__ float part[64][5];
    __shared__ float pl[64];
    __shared__ float mz[2];
    const int b = blockIdx.y;
    const int l0 = blockIdx.x * 64;
    const int t = threadIdx.x;
    // build s_e for this b
    #pragma unroll
    for (int i = 0; i < 2; ++i) {
        int hh = t + i * 256;
        float v = bs[hh];
        #pragma unroll
        for (int s = 0; s < 4; ++s) v += pse[(size_t)s * (B_ * H_) + b * H_ + hh];
        se[hh] = v;
    }
    __syncthreads();
    // pass 1: thread = (l = t&63, w = t>>6 h-range of 128); dot partial
    const int l = t & 63, w = t >> 6;
    const u16* hrow = he + ((size_t)b * L_ + l0 + l) * H_ + w * 128;
    const float* sew = &se[w * 128];
    float dp = 0.f;
    #pragma unroll
    for (int kc = 0; kc < 128; kc += 8) {
        uint4 q = *(const uint4*)(hrow + kc);
        dp += sew[kc + 0] * bflo(q.x) + sew[kc + 1] * bfhi(q.x)
            + sew[kc + 2] * bflo(q.y) + sew[kc + 3] * bfhi(q.y)
            + sew[kc + 4] * bflo(q.z) + sew[kc + 5] * bfhi(q.z)
            + sew[kc + 6] * bflo(q.w) + sew[kc + 7] * bfhi(q.w);
    }
    part[l][w] = dp;
    __syncthreads();
    // wave 0: finalize e, chunk softmax partial
    if (t < 64) {
        float e = part[t][0] + part[t][1] + part[t][2] + part[t][3];
        float m = e;
        #pragma unroll
        for (int off = 1; off < 64; off <<= 1) m = fmaxf(m, __shfl_xor(m, off));
        float p = __expf(e - m);
        float Z = p;
        #pragma unroll
        for (int off = 1; off < 64; off <<= 1) Z += __shfl_xor(Z, off);
        pl[t] = p;
        if (t == 0) { mz[0] = m; mz[1] = Z; }
    }
    __syncthreads();
    // pass 2: thread covers 2 h over all 64 l (tile hot in L2)
    float a0 = 0.f, a1 = 0.f;
    const u16* base2 = he + ((size_t)b * L_ + l0) * H_ + t * 2;
    #pragma unroll 4
    for (int j = 0; j < 64; ++j) {
        u32 q = *(const u32*)(base2 + (size_t)j * H_);
        float p = pl[j];
        a0 += p * bflo(q); a1 += p * bfhi(q);
    }
    float* dst = pa + ((size_t)b * 16 + blockIdx.x) * 520;
    dst[t * 2] = a0; dst[t * 2 + 1] = a1;
    if (t == 0) { dst[512] = mz[0]; dst[513] = mz[1]; }
}

// ---------------- combine 16 chunk-partials -> att ----------------  grid (32 b)
__global__ __launch_bounds__(256) void k_comb(const float* __restrict__ pa,
                                              float* __restrict__ att,
                                              float* __restrict__ out_att, int t) {
    __shared__ float sm[16], sz[16], swt[16], sZt;
    const int b = blockIdx.x;
    const int tid = threadIdx.x;
    if (tid < 16) {
        sm[tid] = pa[((size_t)b * 16 + tid) * 520 + 512];
        sz[tid] = pa[((size_t)b * 16 + tid) * 520 + 513];
    }
    __syncthreads();
    if (tid == 0) {
        float M = sm[0];
        #pragma unroll
        for (int i = 1; i < 16; ++i) M = fmaxf(M, sm[i]);
        float Zt = 0.f;
        #pragma unroll
        for (int i = 0; i < 16; ++i) { float wv = __expf(sm[i] - M); swt[i] = wv; Zt += wv * sz[i]; }
        sZt = Zt;
    }
    __syncthreads();
    const float inv = 1.f / sZt;
    float a0 = 0.f, a1 = 0.f;
    #pragma unroll
    for (int i = 0; i < 16; ++i) {
        const float* p = pa + ((size_t)b * 16 + i) * 520 + tid * 2;
        float wv = swt[i];
        a0 += wv * p[0]; a1 += wv * p[1];
    }
    a0 *= inv; a1 *= inv;
    att[b * H_ + tid * 2] = a0;
    att[b * H_ + tid * 2 + 1] = a1;
    out_att[(size_t)b * (S_ * H_) + t * H_ + tid * 2] = a0;
    out_att[(size_t)b * (S_ * H_) + t * H_ + tid * 2 + 1] = a1;
}

extern "C" void kernel_launch(void* const* d_in, const int* in_sizes, int n_in,
                              void* d_out, int out_size, void* d_ws, size_t ws_size,
                              hipStream_t stream) {
    const float* y   = (const float*)d_in[0];
    const float* enc = (const float*)d_in[1];
    const float* Wih = (const float*)d_in[2];
    const float* bih = (const float*)d_in[3];
    const float* Whh = (const float*)d_in[4];
    const float* bhh = (const float*)d_in[5];
    const float* Ws_ = (const float*)d_in[6];
    const float* bs  = (const float*)d_in[7];
    const float* Wh  = (const float*)d_in[8];
    const float* bh  = (const float*)d_in[9];

    float* ws    = (float*)d_ws;
    u16*   heb   = (u16*)(ws + OFF_HEB);
    u16*   wihb  = (u16*)(ws + OFF_WIHB);
    u16*   whhb  = (u16*)(ws + OFF_WHHB);
    float* h     = ws + OFF_H;
    float* c     = ws + OFF_C;
    float* att   = ws + OFF_ATT;
    float* pg    = ws + OFF_PG;
    float* pse   = ws + OFF_PSE;
    float* pa    = ws + OFF_PA;
    float* out_h   = (float*)d_out;
    float* out_att = out_h + (size_t)B_ * S_ * H_;

    k_zero<<<(3 * B_ * H_ + 255) / 256, 256, 0, stream>>>(h, 3 * B_ * H_);
    k_cvtw<<<(1572864 + 1048576) / 4 / 256, 256, 0, stream>>>(Wih, Whh, wihb, whhb);
    k_he<<<dim3(H_ / 64, (B_ * L_) / 64), 256, 0, stream>>>(enc, Wh, bh, heb);
    for (int t = 0; t < S_; ++t) {
        k_gates<<<dim3(32, 8), 256, 0, stream>>>(y, att, h, wihb, whhb, pg, t);
        k_lstm<<<(B_ * H_) / 256, 256, 0, stream>>>(pg, bih, bhh, c, h, out_h, t);
        k_se<<<dim3(8, 4), 256, 0, stream>>>(h, Ws_, pse);
        k_attn<<<dim3(16, 32), 256, 0, stream>>>(pse, bs, heb, pa);
        k_comb<<<32, 256, 0, stream>>>(pa, att, out_att, t);
    }
}